// Round 10
// baseline (443.323 us; speedup 1.0000x reference)
//
#include <hip/hip_runtime.h>

typedef unsigned short u16;
typedef __bf16 bf16x8 __attribute__((ext_vector_type(8)));
typedef float f32x4 __attribute__((ext_vector_type(4)));

__device__ __forceinline__ u16 f2bf(float f) {
  union { float f; unsigned u; } v; v.f = f;
  unsigned r = (v.u + 0x7FFFu + ((v.u >> 16) & 1u)) >> 16;
  return (u16)r;
}
__device__ __forceinline__ float bf2f(u16 u) {
  union { unsigned u; float f; } v; v.u = ((unsigned)u) << 16;
  return v.f;
}

#define GLD16(g, l) __builtin_amdgcn_global_load_lds((const __attribute__((address_space(1))) void*)(g), (__attribute__((address_space(3))) void*)(l), 16, 0, 0)
#define LOG2E 1.44269504f

// ---------------- mega-prep: 3 weight transposes (convert now fused into gemm256_ax) ----------------
__global__ __launch_bounds__(256) void mega_prep(const float* __restrict__ Wq, u16* __restrict__ WqT,
                                                 const float* __restrict__ Wkv, u16* __restrict__ WkvT,
                                                 const float* __restrict__ Wproj, u16* __restrict__ WprojT) {
  __shared__ float t[32][33];
  int bid = blockIdx.x;
  const float* in; u16* outp; int N;
  const int K = 768;
  if (bid < 576) { in = Wq; outp = WqT; N = 768; }
  else if (bid < 1728) { in = Wkv; outp = WkvT; N = 1536; bid -= 576; }
  else { in = Wproj; outp = WprojT; N = 768; bid -= 1728; }
  int nb = N >> 5;
  int bn = bid % nb, bk = bid / nb;
  int tx = threadIdx.x & 31, ty = threadIdx.x >> 5;
#pragma unroll
  for (int i = 0; i < 4; ++i)
    t[ty + i * 8][tx] = in[(size_t)(bk * 32 + ty + i * 8) * N + bn * 32 + tx];
  __syncthreads();
#pragma unroll
  for (int i = 0; i < 4; ++i)
    outp[(size_t)(bn * 32 + ty + i * 8) * K + bk * 32 + tx] = f2bf(t[tx][ty + i * 8]);
}

// ============ 256x256 8-phase GEMM, A = fp32 source (fused convert), K=768, BK=64 ============
// B via global_load_lds (as verified r4/r6/r8/r9). A reg-staged: load f32 in phase p, cvt+ds_write
// in phase p+2 (one barrier ahead of first read). vmcnt re-derived: A-write waits vmcnt(2);
// B-consume invariants vmcnt(6) at p3/p7 (keep {SB2, LA4}, retire needed B-half).
__global__ __launch_bounds__(512, 2) void gemm256_ax(const float* __restrict__ Af,
                                                     const u16* __restrict__ Bt,
                                                     u16* __restrict__ C,
                                                     int M, int N) {
  __shared__ __align__(16) char smem[131072];
  const int KBf = 3072;  // A fp32 row stride bytes
  const int KB = 1536;   // B bf16 row stride bytes
  int nb = N >> 8;
  int nwg = gridDim.x;
  int bid = blockIdx.x;
  if (!(nwg & 7)) { int cpx = nwg >> 3; bid = (bid & 7) * cpx + (bid >> 3); }
  int bm = bid / nb, bn = bid - bm * nb;
  int tid = threadIdx.x, lane = tid & 63, wid = tid >> 6;
  int wm = wid >> 2, wn = wid & 3;
  int l15 = lane & 15, g4 = lane >> 4;

  // stage patterns: 0=A-ht0 (rows {0-63,128-191}), 1=A-ht1, 2=B-ht0, 3=B-ht1
  int ga32[2][2], gb[2][2], loffA[2][2], loffB[2][2];
#pragma unroll
  for (int p = 0; p < 4; ++p) {
#pragma unroll
    for (int i = 0; i < 2; ++i) {
      int idx = wid * 2 + i;
      int ht = p & 1;
      int base;
      if (p < 2) base = ht * 8192 + (idx >> 3) * 16384 + (idx & 7) * 1024;
      else       base = (idx >> 2) * 8192 + ht * 4096 + (idx & 3) * 1024;
      int pb = base + 16 * lane;
      int lb = pb ^ (((pb >> 9) & 1) << 5);
      if (p < 2) { ga32[p][i] = (lb >> 7) * KBf + (lb & 127) * 2; loffA[p][i] = pb; }
      else       { gb[p - 2][i] = (lb >> 7) * KB + (lb & 127);    loffB[p - 2][i] = pb; }
    }
  }
  const char* Agb = (const char*)Af + (size_t)bm * 256 * KBf;
  const char* Bgb = (const char*)Bt + (size_t)bn * 256 * KB;

  float4 ar[2][2];  // pending A half-tile (16 VGPR)
  auto LDA = [&](int pat, int k0) {
#pragma unroll
    for (int i = 0; i < 2; ++i) {
      const char* s = Agb + ga32[pat][i] + k0 * 4;
      ar[i][0] = *(const float4*)(s);
      ar[i][1] = *(const float4*)(s + 16);
    }
  };
  auto WRA = [&](int pat, int buf) {  // cvt pending regs -> bf16, write linear LDS
#pragma unroll
    for (int i = 0; i < 2; ++i) {
      union { u16 h[8]; uint4 v; } r;
      const float* f0 = (const float*)&ar[i][0];
      const float* f1 = (const float*)&ar[i][1];
#pragma unroll
      for (int e = 0; e < 4; ++e) {
        union { __bf16 b; u16 u; } c0; c0.b = (__bf16)f0[e]; r.h[e] = c0.u;
        union { __bf16 b; u16 u; } c1; c1.b = (__bf16)f1[e]; r.h[4 + e] = c1.u;
      }
      *(uint4*)(smem + buf * 65536 + loffA[pat][i]) = r.v;
    }
  };
  auto SB = [&](int pat, int buf, int k0) {  // B stage via global_load_lds (pat in {0,1} = B-ht)
    int lbase = buf * 65536 + 32768;
#pragma unroll
    for (int i = 0; i < 2; ++i)
      GLD16(Bgb + gb[pat][i] + k0 * 2, smem + lbase + loffB[pat][i]);
  };

  f32x4 acc[8][4];
  const f32x4 fz = {0.f, 0.f, 0.f, 0.f};
#pragma unroll
  for (int a = 0; a < 8; ++a)
#pragma unroll
    for (int b = 0; b < 4; ++b) acc[a][b] = fz;
  bf16x8 af[4][2], bv[2][2];

  auto RDA = [&](int buf, int qm) {
#pragma unroll
    for (int mi = 0; mi < 4; ++mi)
#pragma unroll
      for (int ks = 0; ks < 2; ++ks) {
        int lb = (wm * 128 + qm * 64 + mi * 16 + l15) * 128 + ks * 64 + g4 * 16;
        int pb = lb ^ (((lb >> 9) & 1) << 5);
        af[mi][ks] = *(const bf16x8*)(smem + buf * 65536 + pb);
      }
  };
  auto RDB = [&](int buf, int qn) {
#pragma unroll
    for (int ni = 0; ni < 2; ++ni)
#pragma unroll
      for (int ks = 0; ks < 2; ++ks) {
        int lb = (wn * 64 + qn * 32 + ni * 16 + l15) * 128 + ks * 64 + g4 * 16;
        int pb = lb ^ (((lb >> 9) & 1) << 5);
        bv[ni][ks] = *(const bf16x8*)(smem + buf * 65536 + 32768 + pb);
      }
  };
  auto MM = [&](int qm, int qn) {
    __builtin_amdgcn_s_setprio(1);
#pragma unroll
    for (int mi = 0; mi < 4; ++mi)
#pragma unroll
      for (int ni = 0; ni < 2; ++ni)
#pragma unroll
        for (int ks = 0; ks < 2; ++ks)
          acc[qm * 4 + mi][qn * 2 + ni] =
              __builtin_amdgcn_mfma_f32_16x16x32_bf16(af[mi][ks], bv[ni][ks],
                                                      acc[qm * 4 + mi][qn * 2 + ni], 0, 0, 0);
    __builtin_amdgcn_s_setprio(0);
  };
#define BAR() __builtin_amdgcn_s_barrier()
#define LGKM0() asm volatile("s_waitcnt lgkmcnt(0)" ::: "memory")
#define VMC(n) asm volatile("s_waitcnt vmcnt(" #n ")" ::: "memory")

  // ---- prologue: buf0 fully staged; pending {LA(pat0,64), SB(B-ht0,buf1,64)} to match steady p0 ----
  SB(0, 0, 0); SB(1, 0, 0);     // buf0 B both halves (4 gloads)
  LDA(0, 0);
  VMC(0);
  WRA(0, 0);                    // buf0 A-ht0
  LDA(1, 0);
  VMC(0);
  WRA(1, 0);                    // buf0 A-ht1
  LDA(0, 64);                   // pending -> written at p0 (buf1 A-ht0)
  SB(0, 1, 64);                 // buf1 B-ht0 (pending)
  LGKM0();                      // drain prologue ds_writes before barrier
  BAR();

  for (int t = 0; t < 6; ++t) {
    int kO = t * 128 + 64, kE2 = t * 128 + 128, kO2 = t * 128 + 192;
    bool lst = (t == 5);
    // ---- K-tile even (buf0), phases 0-3 ----
    VMC(2); WRA(0, 1);  RDA(0, 0); RDB(0, 0); LDA(1, kO);            // p0
    BAR(); LGKM0(); MM(0, 0); BAR();
    RDB(0, 1); SB(1, 1, kO);                                          // p1
    BAR(); LGKM0(); MM(0, 1); BAR();
    VMC(2); WRA(1, 1);  RDA(0, 1); RDB(0, 0); if (!lst) LDA(0, kE2);  // p2
    BAR(); LGKM0(); MM(1, 0); BAR();
    RDB(0, 1); if (!lst) SB(0, 0, kE2);                               // p3
    BAR(); LGKM0(); MM(1, 1);
    if (lst) VMC(0); else VMC(6);
    BAR();
    // ---- K-tile odd (buf1), phases 4-7 ----
    if (!lst) { VMC(2); WRA(0, 0); }  RDA(1, 0); RDB(1, 0); if (!lst) LDA(1, kE2);  // p4
    BAR(); LGKM0(); MM(0, 0); BAR();
    RDB(1, 1); if (!lst) SB(1, 0, kE2);                               // p5
    BAR(); LGKM0(); MM(0, 1); BAR();
    if (!lst) { VMC(2); WRA(1, 0); RDA(1, 1); RDB(1, 0); LDA(0, kO2); }
    else      { RDA(1, 1); RDB(1, 0); }                               // p6
    BAR(); LGKM0(); MM(1, 0); BAR();
    RDB(1, 1); if (!lst) SB(0, 1, kO2);                               // p7
    BAR(); LGKM0(); MM(1, 1);
    if (!lst) VMC(6);
    BAR();
  }
#undef BAR
#undef LGKM0
#undef VMC

#pragma unroll
  for (int a = 0; a < 8; ++a)
#pragma unroll
    for (int b = 0; b < 4; ++b)
#pragma unroll
      for (int r = 0; r < 4; ++r)
        C[(size_t)(bm * 256 + wm * 128 + a * 16 + g4 * 4 + r) * N + bn * 256 + wn * 64 + b * 16 + l15] =
            f2bf(acc[a][b][r]);
}

// ---------------- 128x128 GEMM (general M/N): C = scale*A@Bt^T (+bias) ----------------
template <int AF32, int OUTF32>
__global__ __launch_bounds__(256) void gemm_bt(const void* __restrict__ Av,
                                               const u16* __restrict__ Bt,
                                               void* __restrict__ Cv,
                                               const float* __restrict__ bias,
                                               float scale, int M, int N, int K) {
  __shared__ u16 As[128 * 32];
  __shared__ u16 Bs[128 * 32];
  int nb = N >> 7;
  int nwg = gridDim.x;
  int bid = blockIdx.x;
  if (!(nwg & 7)) { int cpx = nwg >> 3; bid = (bid & 7) * cpx + (bid >> 3); }
  int bm = bid / nb, bn = bid - bm * nb;
  int tid = threadIdx.x, lane = tid & 63, w = tid >> 6;
  int wr = w >> 1, wc = w & 1;
  int l15 = lane & 15, g4 = lane >> 4;

  const f32x4 fz = {0.f, 0.f, 0.f, 0.f};
  f32x4 acc[4][4];
#pragma unroll
  for (int m = 0; m < 4; ++m)
#pragma unroll
    for (int n = 0; n < 4; ++n) acc[m][n] = fz;

  const int kIters = K >> 5;
  for (int kt = 0; kt < kIters; ++kt) {
    __syncthreads();
    const int k0 = kt << 5;
    if constexpr (AF32) {
      const float* Af = (const float*)Av;
#pragma unroll
      for (int i = 0; i < 4; ++i) {
        int c = tid + (i << 8);
        int row = c >> 3, cp = c & 7;
        int grow = bm * 128 + row; if (grow > M - 1) grow = M - 1;
        float4 v = *(const float4*)(Af + (size_t)grow * K + k0 + cp * 4);
        ushort4 o; o.x = f2bf(v.x); o.y = f2bf(v.y); o.z = f2bf(v.z); o.w = f2bf(v.w);
        *(ushort4*)&As[row * 32 + cp * 4] = o;
      }
    } else {
      const u16* Ab = (const u16*)Av;
#pragma unroll
      for (int i = 0; i < 2; ++i) {
        int c = tid + (i << 8);
        int row = c >> 2, cp = c & 3;
        int grow = bm * 128 + row; if (grow > M - 1) grow = M - 1;
        GLD16(Ab + (size_t)grow * K + k0 + cp * 8, &As[row * 32 + cp * 8]);
      }
    }
#pragma unroll
    for (int i = 0; i < 2; ++i) {
      int c = tid + (i << 8);
      int row = c >> 2, cp = c & 3;
      GLD16(Bt + (size_t)(bn * 128 + row) * K + k0 + cp * 8, &Bs[row * 32 + cp * 8]);
    }
    __syncthreads();
    bf16x8 af[4], bfr[4];
#pragma unroll
    for (int m = 0; m < 4; ++m)
      af[m] = *(const bf16x8*)&As[(wr * 64 + m * 16 + l15) * 32 + g4 * 8];
#pragma unroll
    for (int n = 0; n < 4; ++n)
      bfr[n] = *(const bf16x8*)&Bs[(wc * 64 + n * 16 + l15) * 32 + g4 * 8];
#pragma unroll
    for (int m = 0; m < 4; ++m)
#pragma unroll
      for (int n = 0; n < 4; ++n)
        acc[m][n] = __builtin_amdgcn_mfma_f32_16x16x32_bf16(af[m], bfr[n], acc[m][n], 0, 0, 0);
  }
  int r0 = bm * 128 + wr * 64;
  int c0 = bn * 128 + wc * 64;
#pragma unroll
  for (int m = 0; m < 4; ++m) {
#pragma unroll
    for (int n = 0; n < 4; ++n) {
      int col = c0 + n * 16 + l15;
      float badd = bias ? bias[col] : 0.f;
#pragma unroll
      for (int r = 0; r < 4; ++r) {
        int grow = r0 + m * 16 + g4 * 4 + r;
        if (grow < M) {
          float v = acc[m][n][r] * scale + badd;
          if constexpr (OUTF32) ((float*)Cv)[(size_t)grow * N + col] = v;
          else ((u16*)Cv)[(size_t)grow * N + col] = f2bf(v);
        }
      }
    }
  }
}

// ---------------- cls reduce over 16 per-frame chunks (partials produced by frame_attn) ----------------
#define CLS_CH 16
__global__ __launch_bounds__(64) void cls_reduce(const float* __restrict__ part,
                                                 u16* __restrict__ ATT) {
  int bh = blockIdx.x;
  int b = bh / 12, h = bh % 12;
  int d = threadIdx.x;
  float m[CLS_CH], l[CLS_CH];
  float M = -1e30f;
#pragma unroll
  for (int c = 0; c < CLS_CH; ++c) {
    m[c] = part[(size_t)(bh * CLS_CH + c) * 66 + 64];
    l[c] = part[(size_t)(bh * CLS_CH + c) * 66 + 65];
    M = fmaxf(M, m[c]);
  }
  float L = 0.f, o = 0.f;
#pragma unroll
  for (int c = 0; c < CLS_CH; ++c) {
    float wgt = exp2f((m[c] - M) * LOG2E) * l[c];
    L += wgt;
    o += wgt * part[(size_t)(bh * CLS_CH + c) * 66 + d];
  }
  ATT[(size_t)(b * 497) * 768 + h * 64 + d] = f2bf(o / L);
}

// ---------------- frame attention v4: rows 1-31 -> ATT; row 0 = cls partial -> PART ----------------
#define VSTR 232
__global__ __launch_bounds__(256, 3) void frame_attn(const u16* __restrict__ Qp,
                                                     const u16* __restrict__ KV,
                                                     u16* __restrict__ ATT,
                                                     float* __restrict__ part) {
  __shared__ u16 Vt[64 * VSTR];
  __shared__ u16 P[32 * VSTR];
  __shared__ float redm[2][32];
  __shared__ float reds[2][32];

  int bid = blockIdx.x;
  int b = bid / 192;
  int h = (bid / 16) % 12;
  int f = bid % 16;
  int tid = threadIdx.x, lane = tid & 63, w = tid >> 6;
  int l15 = lane & 15, g4 = lane >> 4;
  int mt = w >> 1, nh = w & 1;

  const u16* Kb = KV + ((size_t)(b * 3136 + f * 196)) * 1536 + h * 64;
  const u16* Vb = Kb + 768;
  const u16* Qbp = Qp + (size_t)(b * 32) * 768 + h * 64;

  int qrow = mt * 16 + l15;
  bf16x8 qf[2];
  qf[0] = *(const bf16x8*)(Qbp + (size_t)qrow * 768 + g4 * 8);
  qf[1] = *(const bf16x8*)(Qbp + (size_t)qrow * 768 + 32 + g4 * 8);

  bf16x8 kfa[7][2];
#pragma unroll
  for (int nt = 0; nt < 7; ++nt) {
    if (!(nh == 1 && nt == 6)) {
      int j = nh * 112 + nt * 16 + l15;
      kfa[nt][0] = *(const bf16x8*)(Kb + (size_t)j * 1536 + g4 * 8);
      kfa[nt][1] = *(const bf16x8*)(Kb + (size_t)j * 1536 + 32 + g4 * 8);
    }
  }

  int vd8 = tid & 7;
  int vr0 = (tid >> 3) * 2;
  uint4 va[3][2];
#pragma unroll
  for (int i = 0; i < 3; ++i) {
    int j = vr0 + i * 64;
    va[i][0] = *(const uint4*)(Vb + (size_t)j * 1536 + vd8 * 8);
    va[i][1] = *(const uint4*)(Vb + (size_t)(j + 1) * 1536 + vd8 * 8);
  }
  bool vtail = (vr0 < 4);
  uint4 vt0, vt1;
  if (vtail) {
    vt0 = *(const uint4*)(Vb + (size_t)(vr0 + 192) * 1536 + vd8 * 8);
    vt1 = *(const uint4*)(Vb + (size_t)(vr0 + 193) * 1536 + vd8 * 8);
  }
  for (int c = tid; c < 64 * 28; c += 256) {
    int d = c / 28, j = 196 + (c - d * 28);
    Vt[d * VSTR + j] = 0;
  }

  const f32x4 fz = {0.f, 0.f, 0.f, 0.f};
  f32x4 s[7];
#pragma unroll
  for (int i = 0; i < 7; ++i) s[i] = fz;
#pragma unroll
  for (int nt = 0; nt < 7; ++nt) {
    if (!(nh == 1 && nt == 6)) {
      s[nt] = __builtin_amdgcn_mfma_f32_16x16x32_bf16(qf[0], kfa[nt][0], s[nt], 0, 0, 0);
      s[nt] = __builtin_amdgcn_mfma_f32_16x16x32_bf16(qf[1], kfa[nt][1], s[nt], 0, 0, 0);
    }
  }
  const f32x4 fneg = {-1e30f, -1e30f, -1e30f, -1e30f};
#pragma unroll
  for (int nt = 0; nt < 7; ++nt) {
    int j = nh * 112 + nt * 16 + l15;
    if (j >= 196) s[nt] = fneg;
  }
  float pm[4], psum[4];
#pragma unroll
  for (int r = 0; r < 4; ++r) {
    float m = s[0][r];
#pragma unroll
    for (int nt = 1; nt < 7; ++nt) m = fmaxf(m, s[nt][r]);
    m = fmaxf(m, __shfl_xor(m, 1));
    m = fmaxf(m, __shfl_xor(m, 2));
    m = fmaxf(m, __shfl_xor(m, 4));
    m = fmaxf(m, __shfl_xor(m, 8));
    pm[r] = m;
    psum[r] = 0.f;
  }
#pragma unroll
  for (int nt = 0; nt < 7; ++nt)
#pragma unroll
    for (int r = 0; r < 4; ++r) {
      float e = exp2f((s[nt][r] - pm[r]) * LOG2E);
      s[nt][r] = e;
      psum[r] += e;
    }
#pragma unroll
  for (int r = 0; r < 4; ++r) {
    psum[r] += __shfl_xor(psum[r], 1);
    psum[r] += __shfl_xor(psum[r], 2);
    psum[r] += __shfl_xor(psum[r], 4);
    psum[r] += __shfl_xor(psum[r], 8);
  }
  if (l15 == 0) {
#pragma unroll
    for (int r = 0; r < 4; ++r) {
      redm[nh][mt * 16 + g4 * 4 + r] = pm[r];
      reds[nh][mt * 16 + g4 * 4 + r] = psum[r];
    }
  }
  __syncthreads();  // barrier A

#pragma unroll
  for (int i = 0; i < 3; ++i) {
    const u16* a = (const u16*)&va[i][0];
    const u16* bq = (const u16*)&va[i][1];
    int j = vr0 + i * 64;
#pragma unroll
    for (int e = 0; e < 8; ++e) {
      unsigned wv = (unsigned)a[e] | ((unsigned)bq[e] << 16);
      *(unsigned*)&Vt[(vd8 * 8 + e) * VSTR + j] = wv;
    }
  }
  if (vtail) {
    const u16* a = (const u16*)&vt0;
    const u16* bq = (const u16*)&vt1;
    int j = vr0 + 192;
#pragma unroll
    for (int e = 0; e < 8; ++e) {
      unsigned wv = (unsigned)a[e] | ((unsigned)bq[e] << 16);
      *(unsigned*)&Vt[(vd8 * 8 + e) * VSTR + j] = wv;
    }
  }

  float M0 = 0.f, L0 = 1.f;
#pragma unroll
  for (int r = 0; r < 4; ++r) {
    int row = mt * 16 + g4 * 4 + r;
    float m0 = redm[0][row], m1 = redm[1][row];
    float M = fmaxf(m0, m1);
    float L = reds[0][row] * exp2f((m0 - M) * LOG2E) + reds[1][row] * exp2f((m1 - M) * LOG2E);
    if (r == 0) { M0 = M; L0 = L; }
    float fac = exp2f((pm[r] - M) * LOG2E) / L;
#pragma unroll
    for (int nt = 0; nt < 7; ++nt)
      P[row * VSTR + nh * 112 + nt * 16 + l15] = f2bf(s[nt][r] * fac);
  }
  __syncthreads();  // barrier B

  f32x4 o0 = fz, o1 = fz;
  int prow = mt * 16 + l15;
#pragma unroll
  for (int ks = 0; ks < 7; ++ks) {
    bf16x8 pa = *(const bf16x8*)&P[prow * VSTR + ks * 32 + g4 * 8];
    bf16x8 v0 = *(const bf16x8*)&Vt[(nh * 32 + l15) * VSTR + ks * 32 + g4 * 8];
    bf16x8 v1 = *(const bf16x8*)&Vt[(nh * 32 + 16 + l15) * VSTR + ks * 32 + g4 * 8];
    o0 = __builtin_amdgcn_mfma_f32_16x16x32_bf16(pa, v0, o0, 0, 0, 0);
    o1 = __builtin_amdgcn_mfma_f32_16x16x32_bf16(pa, v1, o1, 0, 0, 0);
  }
  u16* Ab = ATT + ((size_t)b * 497) * 768 + h * 64;
#pragma unroll
  for (int r = 0; r < 4; ++r) {
    int qi = mt * 16 + g4 * 4 + r;
    if (qi > 0) {
      size_t ro = (size_t)(f * 31 + qi) * 768;
      Ab[ro + nh * 32 + l15] = f2bf(o0[r]);
      Ab[ro + nh * 32 + 16 + l15] = f2bf(o1[r]);
    }
  }
  if (mt == 0 && g4 == 0) {
    float* po = part + (size_t)(((b * 12 + h) * 16) + f) * 66;
    po[nh * 32 + l15] = o0[0];
    po[nh * 32 + 16 + l15] = o1[0];
    if (nh == 0 && l15 == 0) { po[64] = M0; po[65] = L0; }
  }
}

extern "C" void kernel_launch(void* const* d_in, const int* in_sizes, int n_in,
                              void* d_out, int out_size, void* d_ws, size_t ws_size,
                              hipStream_t stream) {
  const float* x = (const float*)d_in[0];
  const float* question = (const float*)d_in[1];
  const float* Wq = (const float*)d_in[2];
  const float* Wkv = (const float*)d_in[3];
  const float* Wproj = (const float*)d_in[4];
  const float* bproj = (const float*)d_in[5];
  float* out = (float*)d_out;

  char* ws = (char*)d_ws;
  size_t off = 0;
  auto carve = [&](size_t elems) {
    u16* p = (u16*)(ws + off);
    off += ((elems * 2 + 255) & ~(size_t)255);
    return p;
  };
  u16* WqT = carve((size_t)768 * 768);
  u16* WkvT = carve((size_t)1536 * 768);
  u16* WprojT = carve((size_t)768 * 768);
  u16* Qb = carve((size_t)512 * 768);
  u16* KV = carve((size_t)50176 * 1536);
  u16* ATT = carve((size_t)7952 * 768);
  float* PART = (float*)carve((size_t)192 * CLS_CH * 66 * 2);
  if (ws_size < off) return;

  mega_prep<<<576 + 1152 + 576, 256, 0, stream>>>(Wq, WqT, Wkv, WkvT, Wproj, WprojT);
  gemm_bt<1, 0><<<4 * 6, 256, 0, stream>>>(question, WqT, Qb, nullptr, 0.125f, 512, 768, 768);
  gemm256_ax<<<196 * 6, 512, 0, stream>>>(x, WkvT, KV, 50176, 1536);
  frame_attn<<<3072, 256, 0, stream>>>(Qb, KV, ATT, PART);
  cls_reduce<<<192, 64, 0, stream>>>(PART, ATT);
  gemm_bt<0, 1><<<63 * 6, 256, 0, stream>>>(ATT, WprojT, out, bproj, 1.0f, 7952, 768, 768);
}

// Round 11
// 305.112 us; speedup vs baseline: 1.4530x; 1.4530x over previous
//
#include <hip/hip_runtime.h>

typedef unsigned short u16;
typedef __bf16 bf16x8 __attribute__((ext_vector_type(8)));
typedef float f32x4 __attribute__((ext_vector_type(4)));

__device__ __forceinline__ u16 f2bf(float f) {
  union { float f; unsigned u; } v; v.f = f;
  unsigned r = (v.u + 0x7FFFu + ((v.u >> 16) & 1u)) >> 16;
  return (u16)r;
}
__device__ __forceinline__ float bf2f(u16 u) {
  union { unsigned u; float f; } v; v.u = ((unsigned)u) << 16;
  return v.f;
}

#define GLD16(g, l) __builtin_amdgcn_global_load_lds((const __attribute__((address_space(1))) void*)(g), (__attribute__((address_space(3))) void*)(l), 16, 0, 0)
#define LOG2E 1.44269504f

// ---------------- mega-prep: convert x->bf16 + 3 weight transposes, one launch ----------------
__global__ __launch_bounds__(256) void mega_prep(const float* __restrict__ x, u16* __restrict__ xb,
                                                 int have_xb,
                                                 const float* __restrict__ Wq, u16* __restrict__ WqT,
                                                 const float* __restrict__ Wkv, u16* __restrict__ WkvT,
                                                 const float* __restrict__ Wproj, u16* __restrict__ WprojT) {
  __shared__ float t[32][33];
  int bid = blockIdx.x;
  if (bid < 2048) {  // convert role
    if (!have_xb) return;
    const size_t n8 = (size_t)50176 * 768 / 8;
    const size_t stride = (size_t)2048 * 256;
    for (size_t i = (size_t)bid * 256 + threadIdx.x; i < n8; i += stride) {
      float4 a = *(const float4*)(x + i * 8);
      float4 b = *(const float4*)(x + i * 8 + 4);
      ushort4 oa, ob;
      oa.x = f2bf(a.x); oa.y = f2bf(a.y); oa.z = f2bf(a.z); oa.w = f2bf(a.w);
      ob.x = f2bf(b.x); ob.y = f2bf(b.y); ob.z = f2bf(b.z); ob.w = f2bf(b.w);
      ushort4* o = (ushort4*)(xb + i * 8);
      o[0] = oa; o[1] = ob;
    }
    return;
  }
  bid -= 2048;
  const float* in; u16* outp; int N;
  const int K = 768;
  if (bid < 576) { in = Wq; outp = WqT; N = 768; }
  else if (bid < 1728) { in = Wkv; outp = WkvT; N = 1536; bid -= 576; }
  else { in = Wproj; outp = WprojT; N = 768; bid -= 1728; }
  int nb = N >> 5;
  int bn = bid % nb, bk = bid / nb;
  int tx = threadIdx.x & 31, ty = threadIdx.x >> 5;
#pragma unroll
  for (int i = 0; i < 4; ++i)
    t[ty + i * 8][tx] = in[(size_t)(bk * 32 + ty + i * 8) * N + bn * 32 + tx];
  __syncthreads();
#pragma unroll
  for (int i = 0; i < 4; ++i)
    outp[(size_t)(bn * 32 + ty + i * 8) * K + bk * 32 + tx] = f2bf(t[tx][ty + i * 8]);
}

// ============ 256x256 8-phase GEMM (K=768, BK=64, 128KB LDS) — verified r4/r6/r8/r9 version ============
__global__ __launch_bounds__(512, 2) void gemm256_bt(const u16* __restrict__ A,
                                                     const u16* __restrict__ Bt,
                                                     u16* __restrict__ C,
                                                     int M, int N) {
  __shared__ __align__(16) char smem[131072];
  const int KB = 1536;
  int nb = N >> 8;
  int nwg = gridDim.x;
  int bid = blockIdx.x;
  if (!(nwg & 7)) { int cpx = nwg >> 3; bid = (bid & 7) * cpx + (bid >> 3); }
  int bm = bid / nb, bn = bid - bm * nb;
  int tid = threadIdx.x, lane = tid & 63, wid = tid >> 6;
  int wm = wid >> 2, wn = wid & 3;
  int l15 = lane & 15, g4 = lane >> 4;

  int goff[4][2], loff[4][2];
#pragma unroll
  for (int p = 0; p < 4; ++p) {
#pragma unroll
    for (int i = 0; i < 2; ++i) {
      int idx = wid * 2 + i;
      int ht = p & 1;
      int base;
      if (p < 2) base = ht * 8192 + (idx >> 3) * 16384 + (idx & 7) * 1024;
      else       base = (idx >> 2) * 8192 + ht * 4096 + (idx & 3) * 1024;
      int pb = base + 16 * lane;
      int lb = pb ^ (((pb >> 9) & 1) << 5);
      goff[p][i] = (lb >> 7) * KB + (lb & 127);
      loff[p][i] = pb;
    }
  }
  const char* Agb = (const char*)A + (size_t)bm * 256 * KB;
  const char* Bgb = (const char*)Bt + (size_t)bn * 256 * KB;

  auto STAGE = [&](int pat, int buf, int k0) {
    const char* gb = (pat < 2) ? Agb : Bgb;
    int lbase = buf * 65536 + ((pat < 2) ? 0 : 32768);
#pragma unroll
    for (int i = 0; i < 2; ++i)
      GLD16(gb + goff[pat][i] + k0 * 2, smem + lbase + loff[pat][i]);
  };

  f32x4 acc[8][4];
  const f32x4 fz = {0.f, 0.f, 0.f, 0.f};
#pragma unroll
  for (int a = 0; a < 8; ++a)
#pragma unroll
    for (int b = 0; b < 4; ++b) acc[a][b] = fz;
  bf16x8 af[4][2], bv[2][2];

  auto RDA = [&](int buf, int qm) {
#pragma unroll
    for (int mi = 0; mi < 4; ++mi)
#pragma unroll
      for (int ks = 0; ks < 2; ++ks) {
        int lb = (wm * 128 + qm * 64 + mi * 16 + l15) * 128 + ks * 64 + g4 * 16;
        int pb = lb ^ (((lb >> 9) & 1) << 5);
        af[mi][ks] = *(const bf16x8*)(smem + buf * 65536 + pb);
      }
  };
  auto RDB = [&](int buf, int qn) {
#pragma unroll
    for (int ni = 0; ni < 2; ++ni)
#pragma unroll
      for (int ks = 0; ks < 2; ++ks) {
        int lb = (wn * 64 + qn * 32 + ni * 16 + l15) * 128 + ks * 64 + g4 * 16;
        int pb = lb ^ (((lb >> 9) & 1) << 5);
        bv[ni][ks] = *(const bf16x8*)(smem + buf * 65536 + 32768 + pb);
      }
  };
  auto MM = [&](int qm, int qn) {
    __builtin_amdgcn_s_setprio(1);
#pragma unroll
    for (int mi = 0; mi < 4; ++mi)
#pragma unroll
      for (int ni = 0; ni < 2; ++ni)
#pragma unroll
        for (int ks = 0; ks < 2; ++ks)
          acc[qm * 4 + mi][qn * 2 + ni] =
              __builtin_amdgcn_mfma_f32_16x16x32_bf16(af[mi][ks], bv[ni][ks],
                                                      acc[qm * 4 + mi][qn * 2 + ni], 0, 0, 0);
    __builtin_amdgcn_s_setprio(0);
  };
#define BAR() __builtin_amdgcn_s_barrier()
#define LGKM0() asm volatile("s_waitcnt lgkmcnt(0)" ::: "memory")

  STAGE(0, 0, 0); STAGE(2, 0, 0); STAGE(1, 0, 0); STAGE(3, 0, 0);
  STAGE(0, 1, 64); STAGE(2, 1, 64);
  asm volatile("s_waitcnt vmcnt(4)" ::: "memory");
  BAR();

  for (int t = 0; t < 6; ++t) {
    int kO = t * 128 + 64, kE2 = t * 128 + 128, kO2 = t * 128 + 192;
    bool lst = (t == 5);
    RDA(0, 0); RDB(0, 0); STAGE(1, 1, kO);
    BAR(); LGKM0(); MM(0, 0); BAR();
    RDB(0, 1); STAGE(3, 1, kO);
    BAR(); LGKM0(); MM(0, 1); BAR();
    RDA(0, 1); RDB(0, 0); if (!lst) STAGE(0, 0, kE2);
    BAR(); LGKM0(); MM(1, 0); BAR();
    RDB(0, 1); if (!lst) STAGE(2, 0, kE2);
    BAR(); LGKM0(); MM(1, 1);
    if (lst) asm volatile("s_waitcnt vmcnt(0)" ::: "memory");
    else     asm volatile("s_waitcnt vmcnt(4)" ::: "memory");
    BAR();
    RDA(1, 0); RDB(1, 0); if (!lst) STAGE(1, 0, kE2);
    BAR(); LGKM0(); MM(0, 0); BAR();
    RDB(1, 1); if (!lst) STAGE(3, 0, kE2);
    BAR(); LGKM0(); MM(0, 1); BAR();
    RDA(1, 1); RDB(1, 0); if (!lst) STAGE(0, 1, kO2);
    BAR(); LGKM0(); MM(1, 0); BAR();
    RDB(1, 1); if (!lst) STAGE(2, 1, kO2);
    BAR(); LGKM0(); MM(1, 1);
    if (!lst) asm volatile("s_waitcnt vmcnt(4)" ::: "memory");
    BAR();
  }
#undef BAR
#undef LGKM0

#pragma unroll
  for (int a = 0; a < 8; ++a)
#pragma unroll
    for (int b = 0; b < 4; ++b)
#pragma unroll
      for (int r = 0; r < 4; ++r)
        C[(size_t)(bm * 256 + wm * 128 + a * 16 + g4 * 4 + r) * N + bn * 256 + wn * 64 + b * 16 + l15] =
            f2bf(acc[a][b][r]);
}

// ---------------- 128x128 GEMM (general M/N): C = scale*A@Bt^T (+bias) ----------------
template <int AF32, int OUTF32>
__global__ __launch_bounds__(256) void gemm_bt(const void* __restrict__ Av,
                                               const u16* __restrict__ Bt,
                                               void* __restrict__ Cv,
                                               const float* __restrict__ bias,
                                               float scale, int M, int N, int K) {
  __shared__ u16 As[128 * 32];
  __shared__ u16 Bs[128 * 32];
  int nb = N >> 7;
  int nwg = gridDim.x;
  int bid = blockIdx.x;
  if (!(nwg & 7)) { int cpx = nwg >> 3; bid = (bid & 7) * cpx + (bid >> 3); }
  int bm = bid / nb, bn = bid - bm * nb;
  int tid = threadIdx.x, lane = tid & 63, w = tid >> 6;
  int wr = w >> 1, wc = w & 1;
  int l15 = lane & 15, g4 = lane >> 4;

  const f32x4 fz = {0.f, 0.f, 0.f, 0.f};
  f32x4 acc[4][4];
#pragma unroll
  for (int m = 0; m < 4; ++m)
#pragma unroll
    for (int n = 0; n < 4; ++n) acc[m][n] = fz;

  const int kIters = K >> 5;
  for (int kt = 0; kt < kIters; ++kt) {
    __syncthreads();
    const int k0 = kt << 5;
    if constexpr (AF32) {
      const float* Af = (const float*)Av;
#pragma unroll
      for (int i = 0; i < 4; ++i) {
        int c = tid + (i << 8);
        int row = c >> 3, cp = c & 7;
        int grow = bm * 128 + row; if (grow > M - 1) grow = M - 1;
        float4 v = *(const float4*)(Af + (size_t)grow * K + k0 + cp * 4);
        ushort4 o; o.x = f2bf(v.x); o.y = f2bf(v.y); o.z = f2bf(v.z); o.w = f2bf(v.w);
        *(ushort4*)&As[row * 32 + cp * 4] = o;
      }
    } else {
      const u16* Ab = (const u16*)Av;
#pragma unroll
      for (int i = 0; i < 2; ++i) {
        int c = tid + (i << 8);
        int row = c >> 2, cp = c & 3;
        int grow = bm * 128 + row; if (grow > M - 1) grow = M - 1;
        GLD16(Ab + (size_t)grow * K + k0 + cp * 8, &As[row * 32 + cp * 8]);
      }
    }
#pragma unroll
    for (int i = 0; i < 2; ++i) {
      int c = tid + (i << 8);
      int row = c >> 2, cp = c & 3;
      GLD16(Bt + (size_t)(bn * 128 + row) * K + k0 + cp * 8, &Bs[row * 32 + cp * 8]);
    }
    __syncthreads();
    bf16x8 af[4], bfr[4];
#pragma unroll
    for (int m = 0; m < 4; ++m)
      af[m] = *(const bf16x8*)&As[(wr * 64 + m * 16 + l15) * 32 + g4 * 8];
#pragma unroll
    for (int n = 0; n < 4; ++n)
      bfr[n] = *(const bf16x8*)&Bs[(wc * 64 + n * 16 + l15) * 32 + g4 * 8];
#pragma unroll
    for (int m = 0; m < 4; ++m)
#pragma unroll
      for (int n = 0; n < 4; ++n)
        acc[m][n] = __builtin_amdgcn_mfma_f32_16x16x32_bf16(af[m], bfr[n], acc[m][n], 0, 0, 0);
  }
  int r0 = bm * 128 + wr * 64;
  int c0 = bn * 128 + wc * 64;
#pragma unroll
  for (int m = 0; m < 4; ++m) {
#pragma unroll
    for (int n = 0; n < 4; ++n) {
      int col = c0 + n * 16 + l15;
      float badd = bias ? bias[col] : 0.f;
#pragma unroll
      for (int r = 0; r < 4; ++r) {
        int grow = r0 + m * 16 + g4 * 4 + r;
        if (grow < M) {
          float v = acc[m][n][r] * scale + badd;
          if constexpr (OUTF32) ((float*)Cv)[(size_t)grow * N + col] = v;
          else ((u16*)Cv)[(size_t)grow * N + col] = f2bf(v);
        }
      }
    }
  }
}

// ---------------- cls reduce over 16 per-frame chunks (partials produced by frame_attn) ----------------
#define CLS_CH 16
__global__ __launch_bounds__(64) void cls_reduce(const float* __restrict__ part,
                                                 u16* __restrict__ ATT) {
  int bh = blockIdx.x;
  int b = bh / 12, h = bh % 12;
  int d = threadIdx.x;
  float m[CLS_CH], l[CLS_CH];
  float M = -1e30f;
#pragma unroll
  for (int c = 0; c < CLS_CH; ++c) {
    m[c] = part[(size_t)(bh * CLS_CH + c) * 66 + 64];
    l[c] = part[(size_t)(bh * CLS_CH + c) * 66 + 65];
    M = fmaxf(M, m[c]);
  }
  float L = 0.f, o = 0.f;
#pragma unroll
  for (int c = 0; c < CLS_CH; ++c) {
    float wgt = exp2f((m[c] - M) * LOG2E) * l[c];
    L += wgt;
    o += wgt * part[(size_t)(bh * CLS_CH + c) * 66 + d];
  }
  ATT[(size_t)(b * 497) * 768 + h * 64 + d] = f2bf(o / L);
}

// ---------------- frame attention v4: rows 1-31 -> ATT; row 0 = cls partial -> PART ----------------
#define VSTR 232
__global__ __launch_bounds__(256, 3) void frame_attn(const u16* __restrict__ Qp,
                                                     const u16* __restrict__ KV,
                                                     u16* __restrict__ ATT,
                                                     float* __restrict__ part) {
  __shared__ u16 Vt[64 * VSTR];
  __shared__ u16 P[32 * VSTR];
  __shared__ float redm[2][32];
  __shared__ float reds[2][32];

  int bid = blockIdx.x;
  int b = bid / 192;
  int h = (bid / 16) % 12;
  int f = bid % 16;
  int tid = threadIdx.x, lane = tid & 63, w = tid >> 6;
  int l15 = lane & 15, g4 = lane >> 4;
  int mt = w >> 1, nh = w & 1;

  const u16* Kb = KV + ((size_t)(b * 3136 + f * 196)) * 1536 + h * 64;
  const u16* Vb = Kb + 768;
  const u16* Qbp = Qp + (size_t)(b * 32) * 768 + h * 64;

  int qrow = mt * 16 + l15;
  bf16x8 qf[2];
  qf[0] = *(const bf16x8*)(Qbp + (size_t)qrow * 768 + g4 * 8);
  qf[1] = *(const bf16x8*)(Qbp + (size_t)qrow * 768 + 32 + g4 * 8);

  bf16x8 kfa[7][2];
#pragma unroll
  for (int nt = 0; nt < 7; ++nt) {
    if (!(nh == 1 && nt == 6)) {
      int j = nh * 112 + nt * 16 + l15;
      kfa[nt][0] = *(const bf16x8*)(Kb + (size_t)j * 1536 + g4 * 8);
      kfa[nt][1] = *(const bf16x8*)(Kb + (size_t)j * 1536 + 32 + g4 * 8);
    }
  }

  int vd8 = tid & 7;
  int vr0 = (tid >> 3) * 2;
  uint4 va[3][2];
#pragma unroll
  for (int i = 0; i < 3; ++i) {
    int j = vr0 + i * 64;
    va[i][0] = *(const uint4*)(Vb + (size_t)j * 1536 + vd8 * 8);
    va[i][1] = *(const uint4*)(Vb + (size_t)(j + 1) * 1536 + vd8 * 8);
  }
  bool vtail = (vr0 < 4);
  uint4 vt0, vt1;
  if (vtail) {
    vt0 = *(const uint4*)(Vb + (size_t)(vr0 + 192) * 1536 + vd8 * 8);
    vt1 = *(const uint4*)(Vb + (size_t)(vr0 + 193) * 1536 + vd8 * 8);
  }
  for (int c = tid; c < 64 * 28; c += 256) {
    int d = c / 28, j = 196 + (c - d * 28);
    Vt[d * VSTR + j] = 0;
  }

  const f32x4 fz = {0.f, 0.f, 0.f, 0.f};
  f32x4 s[7];
#pragma unroll
  for (int i = 0; i < 7; ++i) s[i] = fz;
#pragma unroll
  for (int nt = 0; nt < 7; ++nt) {
    if (!(nh == 1 && nt == 6)) {
      s[nt] = __builtin_amdgcn_mfma_f32_16x16x32_bf16(qf[0], kfa[nt][0], s[nt], 0, 0, 0);
      s[nt] = __builtin_amdgcn_mfma_f32_16x16x32_bf16(qf[1], kfa[nt][1], s[nt], 0, 0, 0);
    }
  }
  const f32x4 fneg = {-1e30f, -1e30f, -1e30f, -1e30f};
#pragma unroll
  for (int nt = 0; nt < 7; ++nt) {
    int j = nh * 112 + nt * 16 + l15;
    if (j >= 196) s[nt] = fneg;
  }
  float pm[4], psum[4];
#pragma unroll
  for (int r = 0; r < 4; ++r) {
    float m = s[0][r];
#pragma unroll
    for (int nt = 1; nt < 7; ++nt) m = fmaxf(m, s[nt][r]);
    m = fmaxf(m, __shfl_xor(m, 1));
    m = fmaxf(m, __shfl_xor(m, 2));
    m = fmaxf(m, __shfl_xor(m, 4));
    m = fmaxf(m, __shfl_xor(m, 8));
    pm[r] = m;
    psum[r] = 0.f;
  }
#pragma unroll
  for (int nt = 0; nt < 7; ++nt)
#pragma unroll
    for (int r = 0; r < 4; ++r) {
      float e = exp2f((s[nt][r] - pm[r]) * LOG2E);
      s[nt][r] = e;
      psum[r] += e;
    }
#pragma unroll
  for (int r = 0; r < 4; ++r) {
    psum[r] += __shfl_xor(psum[r], 1);
    psum[r] += __shfl_xor(psum[r], 2);
    psum[r] += __shfl_xor(psum[r], 4);
    psum[r] += __shfl_xor(psum[r], 8);
  }
  if (l15 == 0) {
#pragma unroll
    for (int r = 0; r < 4; ++r) {
      redm[nh][mt * 16 + g4 * 4 + r] = pm[r];
      reds[nh][mt * 16 + g4 * 4 + r] = psum[r];
    }
  }
  __syncthreads();  // barrier A

#pragma unroll
  for (int i = 0; i < 3; ++i) {
    const u16* a = (const u16*)&va[i][0];
    const u16* bq = (const u16*)&va[i][1];
    int j = vr0 + i * 64;
#pragma unroll
    for (int e = 0; e < 8; ++e) {
      unsigned wv = (unsigned)a[e] | ((unsigned)bq[e] << 16);
      *(unsigned*)&Vt[(vd8 * 8 + e) * VSTR + j] = wv;
    }
  }
  if (vtail) {
    const u16* a = (const u16*)&vt0;
    const u16* bq = (const u16*)&vt1;
    int j = vr0 + 192;
#pragma unroll
    for (int e = 0; e < 8; ++e) {
      unsigned wv = (unsigned)a[e] | ((unsigned)bq[e] << 16);
      *(unsigned*)&Vt[(vd8 * 8 + e) * VSTR + j] = wv;
    }
  }

  float M0 = 0.f, L0 = 1.f;
#pragma unroll
  for (int r = 0; r < 4; ++r) {
    int row = mt * 16 + g4 * 4 + r;
    float m0 = redm[0][row], m1 = redm[1][row];
    float M = fmaxf(m0, m1);
    float L = reds[0][row] * exp2f((m0 - M) * LOG2E) + reds[1][row] * exp2f((m1 - M) * LOG2E);
    if (r == 0) { M0 = M; L0 = L; }
    float fac = exp2f((pm[r] - M) * LOG2E) / L;
#pragma unroll
    for (int nt = 0; nt < 7; ++nt)
      P[row * VSTR + nh * 112 + nt * 16 + l15] = f2bf(s[nt][r] * fac);
  }
  __syncthreads();  // barrier B

  f32x4 o0 = fz, o1 = fz;
  int prow = mt * 16 + l15;
#pragma unroll
  for (int ks = 0; ks < 7; ++ks) {
    bf16x8 pa = *(const bf16x8*)&P[prow * VSTR + ks * 32 + g4 * 8];
    bf16x8 v0 = *(const bf16x8*)&Vt[(nh * 32 + l15) * VSTR + ks * 32 + g4 * 8];
    bf16x8 v1 = *(const bf16x8*)&Vt[(nh * 32 + 16 + l15) * VSTR + ks * 32 + g4 * 8];
    o0 = __builtin_amdgcn_mfma_f32_16x16x32_bf16(pa, v0, o0, 0, 0, 0);
    o1 = __builtin_amdgcn_mfma_f32_16x16x32_bf16(pa, v1, o1, 0, 0, 0);
  }
  u16* Ab = ATT + ((size_t)b * 497) * 768 + h * 64;
#pragma unroll
  for (int r = 0; r < 4; ++r) {
    int qi = mt * 16 + g4 * 4 + r;
    if (qi > 0) {
      size_t ro = (size_t)(f * 31 + qi) * 768;
      Ab[ro + nh * 32 + l15] = f2bf(o0[r]);
      Ab[ro + nh * 32 + 16 + l15] = f2bf(o1[r]);
    }
  }
  if (mt == 0 && g4 == 0) {
    float* po = part + (size_t)(((b * 12 + h) * 16) + f) * 66;
    po[nh * 32 + l15] = o0[0];
    po[nh * 32 + 16 + l15] = o1[0];
    if (nh == 0 && l15 == 0) { po[64] = M0; po[65] = L0; }
  }
}

extern "C" void kernel_launch(void* const* d_in, const int* in_sizes, int n_in,
                              void* d_out, int out_size, void* d_ws, size_t ws_size,
                              hipStream_t stream) {
  const float* x = (const float*)d_in[0];
  const float* question = (const float*)d_in[1];
  const float* Wq = (const float*)d_in[2];
  const float* Wkv = (const float*)d_in[3];
  const float* Wproj = (const float*)d_in[4];
  const float* bproj = (const float*)d_in[5];
  float* out = (float*)d_out;

  char* ws = (char*)d_ws;
  size_t off = 0;
  auto carve = [&](size_t elems) {
    u16* p = (u16*)(ws + off);
    off += ((elems * 2 + 255) & ~(size_t)255);
    return p;
  };
  u16* WqT = carve((size_t)768 * 768);
  u16* WkvT = carve((size_t)1536 * 768);
  u16* WprojT = carve((size_t)768 * 768);
  u16* Qb = carve((size_t)512 * 768);
  u16* KV = carve((size_t)50176 * 1536);
  u16* ATT = carve((size_t)7952 * 768);
  float* PART = (float*)carve((size_t)192 * CLS_CH * 66 * 2);
  size_t base_need = off;
  u16* xb = carve((size_t)50176 * 768);
  if (ws_size < base_need) return;
  int have_xb = (ws_size >= off) ? 1 : 0;

  mega_prep<<<2048 + 576 + 1152 + 576, 256, 0, stream>>>(x, xb, have_xb,
                                                         Wq, WqT, Wkv, WkvT, Wproj, WprojT);
  gemm_bt<1, 0><<<4 * 6, 256, 0, stream>>>(question, WqT, Qb, nullptr, 0.125f, 512, 768, 768);
  if (have_xb) {
    gemm256_bt<<<196 * 6, 512, 0, stream>>>(xb, WkvT, KV, 50176, 1536);
  } else {
    gemm_bt<1, 0><<<392 * 12, 256, 0, stream>>>(x, WkvT, KV, nullptr, 1.0f, 50176, 1536, 768);
  }
  frame_attn<<<3072, 256, 0, stream>>>(Qb, KV, ATT, PART);
  cls_reduce<<<192, 64, 0, stream>>>(PART, ATT);
  gemm_bt<0, 1><<<63 * 6, 256, 0, stream>>>(ATT, WprojT, out, bproj, 1.0f, 7952, 768, 768);
}